// Round 2
// baseline (6475.604 us; speedup 1.0000x reference)
//
#include <hip/hip_runtime.h>

// TimeLSTM persistent-scan kernel for MI355X (gfx950), round 2.
// Grid: 128 blocks x 320 threads. grp = blockIdx&3 owns batches grp*16..+15;
// member = blockIdx>>2 owns columns member*16..+15 of each gate and of W_d.
// Weights live in VGPRs as f16 MFMA B-fragments for all 1024 steps.
//
// Round-2 change: the per-step h/c exchange uses agent-scope RELAXED atomics
// for BOTH data (packed (c<<16|h) dwords, qword gather) and the barrier
// counter. Agent-scope atomics are serviced at the coherence point (MALL),
// so no release/acquire fence — and therefore no per-step buffer_wbl2 L2
// flush / buffer_inv L2 invalidate — is needed. Ordering: __syncthreads()
// drains vmcnt(0) (stores ack'd at coherence point) before the arrive.

typedef _Float16 f16;
typedef _Float16 f16x8 __attribute__((ext_vector_type(8)));
typedef float f32x4 __attribute__((ext_vector_type(4)));

#define S_ 1024
#define IN_ 256
#define H_ 512
#define ECONST 2.718281828459045f

__device__ __forceinline__ float sigf(float x) { return 1.0f / (1.0f + __expf(-x)); }
__device__ __forceinline__ float tanh_f(float x) { return 1.0f - 2.0f / (__expf(2.0f * x) + 1.0f); }

__device__ __forceinline__ unsigned int pack_hc(float h, float c) {
    union { f16 f; unsigned short u; } ph, pc;
    ph.f = (f16)h; pc.f = (f16)c;
    return ((unsigned int)pc.u << 16) | (unsigned int)ph.u;
}

__launch_bounds__(320, 2)
__global__ void tlstm_scan(
    const float* __restrict__ inputs, const float* __restrict__ tstamps,
    const int* __restrict__ lens,
    const float* __restrict__ W_all, const float* __restrict__ b_all,
    const float* __restrict__ U_all, const float* __restrict__ b_u,
    const float* __restrict__ W_d, const float* __restrict__ b_d,
    float* __restrict__ out0, float* __restrict__ out1, float* __restrict__ out2,
    unsigned long long* __restrict__ hcbuf, unsigned int* __restrict__ cnt)
{
    // LDS: A operand (h: kb 0..63, x_t: kb 64..95) and c operand in MFMA
    // fragment interleave [kb][m][8] (2-way bank aliasing = free).
    __shared__ __align__(16) f16 A_sm[96 * 16 * 8];   // 24 KB
    __shared__ __align__(16) f16 C_sm[64 * 16 * 8];   // 16 KB
    __shared__ float outs_sm[5 * 16 * 17];            // +1 pad on col
    __shared__ float c_loc[16 * 16];                  // fp32 c state (own cells)
    __shared__ float bias_sm[5 * 16];
    __shared__ int   len_sm[16];

    const int tid    = threadIdx.x;
    const int grp    = blockIdx.x & 3;
    const int member = blockIdx.x >> 2;
    const int wave   = tid >> 6;
    const int lane   = tid & 63;
    const int q      = lane >> 4;   // quad
    const int r16    = lane & 15;   // A: m / B: n / C: col
    const int j0     = member * 16;

    // ---------- preload weights into VGPRs as B-fragments ----------
    // B[k][n]: n = lane&15, k = kk*32 + q*8 + e
    f16x8 bw[24];
    if (wave < 4) {
        const int col = wave * 512 + j0 + r16;
#pragma unroll
        for (int kk = 0; kk < 24; ++kk) {
            f16x8 v;
            const int kbase = kk * 32 + q * 8;
#pragma unroll
            for (int e = 0; e < 8; ++e) {
                const int k = kbase + e;
                const float w = (kk < 16) ? W_all[k * 2048 + col]
                                          : U_all[(k - 512) * 2048 + col];
                v[e] = (f16)w;
            }
            bw[kk] = v;
        }
    } else {
        const int col = j0 + r16;
#pragma unroll
        for (int kk = 0; kk < 16; ++kk) {
            f16x8 v;
            const int kbase = kk * 32 + q * 8;
#pragma unroll
            for (int e = 0; e < 8; ++e) v[e] = (f16)W_d[(kbase + e) * 512 + col];
            bw[kk] = v;
        }
#pragma unroll
        for (int kk = 16; kk < 24; ++kk) bw[kk] = bw[0];
    }

    // ---------- init LDS state ----------
    {
        uint4 z; z.x = z.y = z.z = z.w = 0u;
        uint4* a4 = (uint4*)A_sm;
        uint4* c4 = (uint4*)C_sm;
        for (int i = tid; i < 1024; i += 320) { a4[i] = z; c4[i] = z; }
        if (tid < 256) c_loc[tid] = 0.0f;
        if (tid < 64) {
            const int w = tid >> 4, n = tid & 15;
            const int col = w * 512 + j0 + n;
            bias_sm[w * 16 + n] = b_all[col] + b_u[col];
        } else if (tid < 80) {
            const int n = tid & 15;
            bias_sm[64 + n] = b_d[j0 + n];
        }
        if (tid < 16) len_sm[tid] = lens[grp * 16 + tid];
        // stage x(0) into A_sm kb 64..95
        for (int idx = tid; idx < 1024; idx += 320) {
            const int b = idx >> 6;
            const int kx0 = (idx & 63) << 2;
            const float4 v = *(const float4*)&inputs[(((size_t)(grp * 16 + b)) * S_ + 0) * IN_ + kx0];
            union { f16 h[4]; uint2 u; } p;
            p.h[0] = (f16)v.x; p.h[1] = (f16)v.y; p.h[2] = (f16)v.z; p.h[3] = (f16)v.w;
            const int kb = 64 + (kx0 >> 3), e = kx0 & 7;
            *(uint2*)&A_sm[(kb * 16 + b) * 8 + e] = p.u;
        }
    }
    __syncthreads();

    // per-group exchange buffer: 2 phases x 4096 qwords (32 KB per phase)
    unsigned long long* const hc_g = hcbuf + (size_t)grp * 2 * 4096;
    unsigned int* const mycnt = cnt + grp * 32;   // 128B-separated counters

    for (int t = 0; t < S_; ++t) {
        // ---------- MFMA phase ----------
        f32x4 acc0 = {0.f, 0.f, 0.f, 0.f}, acc1 = {0.f, 0.f, 0.f, 0.f};
        if (wave < 4) {
            const f16* abase = &A_sm[(q * 16 + r16) * 8];
#pragma unroll
            for (int kk = 0; kk < 24; ++kk) {
                const f16x8 a = *(const f16x8*)(abase + kk * 512);
                if (kk & 1) acc1 = __builtin_amdgcn_mfma_f32_16x16x32_f16(a, bw[kk], acc1, 0, 0, 0);
                else        acc0 = __builtin_amdgcn_mfma_f32_16x16x32_f16(a, bw[kk], acc0, 0, 0, 0);
            }
        } else {
            const f16* abase = &C_sm[(q * 16 + r16) * 8];
#pragma unroll
            for (int kk = 0; kk < 16; ++kk) {
                const f16x8 a = *(const f16x8*)(abase + kk * 512);
                if (kk & 1) acc1 = __builtin_amdgcn_mfma_f32_16x16x32_f16(a, bw[kk], acc1, 0, 0, 0);
                else        acc0 = __builtin_amdgcn_mfma_f32_16x16x32_f16(a, bw[kk], acc0, 0, 0, 0);
            }
        }
        const f32x4 acc = acc0 + acc1;
        // C/D: col = lane&15, row = quad*4 + reg  (row = batch)
#pragma unroll
        for (int r = 0; r < 4; ++r)
            outs_sm[(wave * 16 + q * 4 + r) * 17 + r16] = acc[r];
        __syncthreads();

        // ---------- elementwise gates ----------
        if (tid < 256) {
            const int b = tid >> 4, jj = tid & 15;
            const int gb = grp * 16 + b;
            const float f  = outs_sm[(0 * 16 + b) * 17 + jj] + bias_sm[0  + jj];
            const float i_ = outs_sm[(1 * 16 + b) * 17 + jj] + bias_sm[16 + jj];
            const float o  = outs_sm[(2 * 16 + b) * 17 + jj] + bias_sm[32 + jj];
            const float ct = outs_sm[(3 * 16 + b) * 17 + jj] + bias_sm[48 + jj];
            const float d  = outs_sm[(4 * 16 + b) * 17 + jj] + bias_sm[64 + jj];
            const float ts = tstamps[(size_t)gb * S_ + t];
            const float gt = 1.0f / __logf(ECONST + ts);
            const float cs1   = tanh_f(d);
            const float cprev = c_loc[tid];
            const float cadj  = cprev - cs1 + cs1 * gt;
            const float cnew  = sigf(f) * cadj + sigf(i_) * tanh_f(ct);
            const float hnew  = sigf(o) * tanh_f(cnew);
            c_loc[tid] = cnew;
            const int col = j0 + jj;
            const int len = len_sm[b];
            out0[((size_t)gb * S_ + t) * H_ + col] = (t < len) ? hnew : 0.0f;
            if (t == len - 1) {
                out1[gb * H_ + col] = hnew;
                out2[gb * H_ + col] = cnew;
            }
            // publish packed (c,h) cell — agent-scope atomic store goes to the
            // coherence point (MALL), bypassing L1/L2: no fence needed.
            const int didx = ((col >> 3) * 16 + b) * 8 + (col & 7);
            unsigned int* dw = (unsigned int*)(hc_g + (size_t)(t & 1) * 4096);
            __hip_atomic_store(dw + didx, pack_hc(hnew, cnew),
                               __ATOMIC_RELAXED, __HIP_MEMORY_SCOPE_AGENT);
        }
        __syncthreads();   // s_waitcnt vmcnt(0) drain: all slice stores ack'd

        if (t < S_ - 1) {
            if (tid == 0) {
                __hip_atomic_fetch_add(mycnt, 1u, __ATOMIC_RELAXED, __HIP_MEMORY_SCOPE_AGENT);
                const unsigned int target = 32u * (unsigned)(t + 1);
                while (__hip_atomic_load(mycnt, __ATOMIC_RELAXED, __HIP_MEMORY_SCOPE_AGENT) < target) {}
            } else if (tid >= 64) {
                // prefetch x(t+1) while thread 0 spins (independent data)
                for (int idx = tid - 64; idx < 1024; idx += 256) {
                    const int b = idx >> 6;
                    const int kx0 = (idx & 63) << 2;
                    const float4 v = *(const float4*)&inputs[(((size_t)(grp * 16 + b)) * S_ + (t + 1)) * IN_ + kx0];
                    union { f16 h[4]; uint2 u; } p;
                    p.h[0] = (f16)v.x; p.h[1] = (f16)v.y; p.h[2] = (f16)v.z; p.h[3] = (f16)v.w;
                    const int kb = 64 + (kx0 >> 3), e = kx0 & 7;
                    *(uint2*)&A_sm[(kb * 16 + b) * 8 + e] = p.u;
                }
            }
            __syncthreads();
            // gather all 32 slices: 4096 qword agent-scope atomic loads
            // (serviced at MALL — coherent, no acquire fence / L2 inv).
            const unsigned long long* src = hc_g + (size_t)(t & 1) * 4096;
            unsigned int* ah = (unsigned int*)A_sm;
            unsigned int* ac = (unsigned int*)C_sm;
            for (int i = tid; i < 4096; i += 320) {
                const unsigned long long v =
                    __hip_atomic_load(src + i, __ATOMIC_RELAXED, __HIP_MEMORY_SCOPE_AGENT);
                const unsigned int d0 = (unsigned int)v;
                const unsigned int d1 = (unsigned int)(v >> 32);
                ah[i] = (d0 & 0xFFFFu) | (d1 << 16);          // h pair
                ac[i] = (d0 >> 16) | (d1 & 0xFFFF0000u);      // c pair
            }
            __syncthreads();
        }
    }
}

extern "C" void kernel_launch(void* const* d_in, const int* in_sizes, int n_in,
                              void* d_out, int out_size, void* d_ws, size_t ws_size,
                              hipStream_t stream) {
    const float* inputs  = (const float*)d_in[0];
    const float* tstamps = (const float*)d_in[1];
    const int*   lens    = (const int*)d_in[2];
    const float* W_all   = (const float*)d_in[3];
    const float* b_all   = (const float*)d_in[4];
    const float* U_all   = (const float*)d_in[5];
    const float* b_u     = (const float*)d_in[6];
    const float* W_d     = (const float*)d_in[7];
    const float* b_d     = (const float*)d_in[8];

    float* out0 = (float*)d_out;                    // [64,1024,512]
    float* out1 = out0 + (size_t)64 * 1024 * 512;   // last_h [64,512]
    float* out2 = out1 + (size_t)64 * 512;          // last_c [64,512]

    char* ws = (char*)d_ws;
    unsigned int* cnt = (unsigned int*)ws;                    // 4 counters, 128B apart
    unsigned long long* hcbuf = (unsigned long long*)(ws + 1024);  // 4 grp * 2 * 32KB = 256KB

    // barrier counters must start at 0 every call (ws is poisoned 0xAA)
    hipMemsetAsync(ws, 0, 1024, stream);

    tlstm_scan<<<dim3(128), dim3(320), 0, stream>>>(
        inputs, tstamps, lens, W_all, b_all, U_all, b_u, W_d, b_d,
        out0, out1, out2, hcbuf, cnt);
}

// Round 3
// 3487.800 us; speedup vs baseline: 1.8566x; 1.8566x over previous
//
#include <hip/hip_runtime.h>

// TimeLSTM persistent-scan kernel for MI355X (gfx950), round 3.
// Grid: 128 blocks x 320 threads. grp = blockIdx&3 owns batches grp*16..+15;
// member = blockIdx>>2 owns columns member*16..+15 of each gate and of W_d.
// Weights live in VGPRs as f16 MFMA B-fragments for all 1024 steps.
//
// Round-3 change: decentralized per-slice flag protocol replaces the counter
// barrier. Producer: publish slice (MALL atomic dword stores, coalesced) ->
// __syncthreads (vmcnt drain = data ack'd) -> flag[member]=t+1 (monotone tag).
// Consumers: each wave polls its 6-7 slices' flags lane-parallel (1 RT per
// poll via ballot), then batch-issues all data loads (1 RT), unpacks to LDS.
// Own slice goes straight to LDS, never through global. ts(t) and x(t+1)
// loads are issued so their latency hides under MFMA / flag visibility.

typedef _Float16 f16;
typedef _Float16 f16x8 __attribute__((ext_vector_type(8)));
typedef float f32x4 __attribute__((ext_vector_type(4)));

#define S_ 1024
#define IN_ 256
#define H_ 512
#define ECONST 2.718281828459045f

__device__ __forceinline__ float sigf(float x) { return 1.0f / (1.0f + __expf(-x)); }
__device__ __forceinline__ float tanh_f(float x) { return 1.0f - 2.0f / (__expf(2.0f * x) + 1.0f); }

__device__ __forceinline__ unsigned int pack_hc(float h, float c) {
    union { f16 f; unsigned short u; } ph, pc;
    ph.f = (f16)h; pc.f = (f16)c;
    return ((unsigned int)pc.u << 16) | (unsigned int)ph.u;
}

__launch_bounds__(320, 2)
__global__ void tlstm_scan(
    const float* __restrict__ inputs, const float* __restrict__ tstamps,
    const int* __restrict__ lens,
    const float* __restrict__ W_all, const float* __restrict__ b_all,
    const float* __restrict__ U_all, const float* __restrict__ b_u,
    const float* __restrict__ W_d, const float* __restrict__ b_d,
    float* __restrict__ out0, float* __restrict__ out1, float* __restrict__ out2,
    unsigned long long* __restrict__ hcbuf, unsigned int* __restrict__ flags)
{
    __shared__ __align__(16) f16 A_sm[96 * 16 * 8];   // 24 KB  (h: kb0..63, x: kb64..95)
    __shared__ __align__(16) f16 C_sm[64 * 16 * 8];   // 16 KB  (c operand)
    __shared__ float outs_sm[5 * 16 * 17];            // +1 pad on col
    __shared__ float c_loc[16 * 16];                  // fp32 c state (own cells)
    __shared__ float bias_sm[5 * 16];
    __shared__ int   len_sm[16];

    const int tid    = threadIdx.x;
    const int grp    = blockIdx.x & 3;
    const int member = blockIdx.x >> 2;
    const int wave   = tid >> 6;
    const int lane   = tid & 63;
    const int q      = lane >> 4;   // quad
    const int r16    = lane & 15;   // A: m / B: n / C: col
    const int j0     = member * 16;

    // ---------- preload weights into VGPRs as B-fragments ----------
    // B[k][n]: n = lane&15, k = kk*32 + q*8 + e
    f16x8 bw[24];
    if (wave < 4) {
        const int col = wave * 512 + j0 + r16;
#pragma unroll
        for (int kk = 0; kk < 24; ++kk) {
            f16x8 v;
            const int kbase = kk * 32 + q * 8;
#pragma unroll
            for (int e = 0; e < 8; ++e) {
                const int k = kbase + e;
                const float w = (kk < 16) ? W_all[k * 2048 + col]
                                          : U_all[(k - 512) * 2048 + col];
                v[e] = (f16)w;
            }
            bw[kk] = v;
        }
    } else {
        const int col = j0 + r16;
#pragma unroll
        for (int kk = 0; kk < 16; ++kk) {
            f16x8 v;
            const int kbase = kk * 32 + q * 8;
#pragma unroll
            for (int e = 0; e < 8; ++e) v[e] = (f16)W_d[(kbase + e) * 512 + col];
            bw[kk] = v;
        }
#pragma unroll
        for (int kk = 16; kk < 24; ++kk) bw[kk] = bw[0];
    }

    // slice list for this wave (6-7 remote slices, round-robin over 5 waves)
    int sl[7];
    int ns = 0;
    for (int s = wave; s < 32; s += 5)
        if (s != member) sl[ns++] = s;

    // ---------- init LDS state ----------
    {
        uint4 z; z.x = z.y = z.z = z.w = 0u;
        uint4* a4 = (uint4*)A_sm;
        uint4* c4 = (uint4*)C_sm;
        for (int i = tid; i < 1024; i += 320) { a4[i] = z; c4[i] = z; }
        if (tid < 256) c_loc[tid] = 0.0f;
        if (tid < 64) {
            const int w = tid >> 4, n = tid & 15;
            const int col = w * 512 + j0 + n;
            bias_sm[w * 16 + n] = b_all[col] + b_u[col];
        } else if (tid < 80) {
            const int n = tid & 15;
            bias_sm[64 + n] = b_d[j0 + n];
        }
        if (tid < 16) len_sm[tid] = lens[grp * 16 + tid];
        // stage x(0) into A_sm kb 64..95
        for (int idx = tid; idx < 1024; idx += 320) {
            const int b = idx >> 6;
            const int kx0 = (idx & 63) << 2;
            const float4 v = *(const float4*)&inputs[(((size_t)(grp * 16 + b)) * S_ + 0) * IN_ + kx0];
            union { f16 h[4]; uint2 u; } p;
            p.h[0] = (f16)v.x; p.h[1] = (f16)v.y; p.h[2] = (f16)v.z; p.h[3] = (f16)v.w;
            const int kb = 64 + (kx0 >> 3), e = kx0 & 7;
            *(uint2*)&A_sm[(kb * 16 + b) * 8 + e] = p.u;
        }
    }
    __syncthreads();

    // per-group exchange buffer: 2 phases x 4096 qwords (32 KB per phase)
    unsigned long long* const hc_g = hcbuf + (size_t)grp * 2 * 4096;
    unsigned int* const flg = flags + grp * 32;

    for (int t = 0; t < S_; ++t) {
        // ts(t) prefetch — overlaps the MFMA phase below
        float ts = 0.0f;
        if (tid < 256) {
            const int gb = grp * 16 + (tid >> 4);
            ts = tstamps[(size_t)gb * S_ + t];
        }

        // ---------- MFMA phase ----------
        f32x4 acc0 = {0.f, 0.f, 0.f, 0.f}, acc1 = {0.f, 0.f, 0.f, 0.f};
        if (wave < 4) {
            const f16* abase = &A_sm[(q * 16 + r16) * 8];
#pragma unroll
            for (int kk = 0; kk < 24; ++kk) {
                const f16x8 a = *(const f16x8*)(abase + kk * 512);
                if (kk & 1) acc1 = __builtin_amdgcn_mfma_f32_16x16x32_f16(a, bw[kk], acc1, 0, 0, 0);
                else        acc0 = __builtin_amdgcn_mfma_f32_16x16x32_f16(a, bw[kk], acc0, 0, 0, 0);
            }
        } else {
            const f16* abase = &C_sm[(q * 16 + r16) * 8];
#pragma unroll
            for (int kk = 0; kk < 16; ++kk) {
                const f16x8 a = *(const f16x8*)(abase + kk * 512);
                if (kk & 1) acc1 = __builtin_amdgcn_mfma_f32_16x16x32_f16(a, bw[kk], acc1, 0, 0, 0);
                else        acc0 = __builtin_amdgcn_mfma_f32_16x16x32_f16(a, bw[kk], acc0, 0, 0, 0);
            }
        }
        const f32x4 acc = acc0 + acc1;
        // C/D: col = lane&15, row = quad*4 + reg  (row = batch)
#pragma unroll
        for (int r = 0; r < 4; ++r)
            outs_sm[(wave * 16 + q * 4 + r) * 17 + r16] = acc[r];
        __syncthreads();

        // ---------- elementwise gates ----------
        if (tid < 256) {
            const int b = tid >> 4, jj = tid & 15;
            const int gb = grp * 16 + b;
            const float f  = outs_sm[(0 * 16 + b) * 17 + jj] + bias_sm[0  + jj];
            const float i_ = outs_sm[(1 * 16 + b) * 17 + jj] + bias_sm[16 + jj];
            const float o  = outs_sm[(2 * 16 + b) * 17 + jj] + bias_sm[32 + jj];
            const float ct = outs_sm[(3 * 16 + b) * 17 + jj] + bias_sm[48 + jj];
            const float d  = outs_sm[(4 * 16 + b) * 17 + jj] + bias_sm[64 + jj];
            const float gt = 1.0f / __logf(ECONST + ts);
            const float cs1   = tanh_f(d);
            const float cprev = c_loc[tid];
            const float cadj  = cprev - cs1 + cs1 * gt;
            const float cnew  = sigf(f) * cadj + sigf(i_) * tanh_f(ct);
            const float hnew  = sigf(o) * tanh_f(cnew);
            c_loc[tid] = cnew;
            const int col = j0 + jj;
            const int len = len_sm[b];
            out0[((size_t)gb * S_ + t) * H_ + col] = (t < len) ? hnew : 0.0f;
            if (t == len - 1) {
                out1[gb * H_ + col] = hnew;
                out2[gb * H_ + col] = cnew;
            }
            // own slice straight into LDS operands (never gathered)
            const int fi = ((col >> 3) * 16 + b) * 8 + (col & 7);
            ((f16*)A_sm)[fi] = (f16)hnew;
            ((f16*)C_sm)[fi] = (f16)cnew;
            // publish packed (c,h): dword idx = member*256 + tid (contiguous 1KB)
            unsigned int* dw = (unsigned int*)(hc_g + (size_t)(t & 1) * 4096);
            __hip_atomic_store(dw + member * 256 + tid, pack_hc(hnew, cnew),
                               __ATOMIC_RELAXED, __HIP_MEMORY_SCOPE_AGENT);
        }
        __syncthreads();   // per-wave vmcnt(0) drain: publish stores ack'd at MALL

        if (t < S_ - 1) {
            const unsigned int tag = (unsigned int)(t + 1);
            if (tid == 0)
                __hip_atomic_store(&flg[member], tag,
                                   __ATOMIC_RELAXED, __HIP_MEMORY_SCOPE_AGENT);

            // issue x(t+1) loads now; latency hides under flag visibility
            float4 xv[4];
            if (tid < 256) {
#pragma unroll
                for (int k2 = 0; k2 < 4; ++k2) {
                    const int idx = k2 * 256 + tid;
                    const int b = idx >> 6;
                    const int kx0 = (idx & 63) << 2;
                    xv[k2] = *(const float4*)&inputs[(((size_t)(grp * 16 + b)) * S_ + (t + 1)) * IN_ + kx0];
                }
            }

            // lane-parallel flag wait for this wave's slices
            for (;;) {
                unsigned int fl = tag;
                if (lane < ns)
                    fl = __hip_atomic_load(&flg[sl[lane]],
                                           __ATOMIC_RELAXED, __HIP_MEMORY_SCOPE_AGENT);
                if (__ballot(fl >= tag) == ~0ull) break;
            }

            // batched gather: 2 qwords per lane per slice, single wait
            const unsigned long long* src = hc_g + (size_t)(t & 1) * 4096;
            unsigned long long v[7][2];
#pragma unroll
            for (int u = 0; u < 7; ++u) {
                if (u < ns) {
                    const int s = sl[u];
                    v[u][0] = __hip_atomic_load(src + s * 128 + lane,
                                                __ATOMIC_RELAXED, __HIP_MEMORY_SCOPE_AGENT);
                    v[u][1] = __hip_atomic_load(src + s * 128 + 64 + lane,
                                                __ATOMIC_RELAXED, __HIP_MEMORY_SCOPE_AGENT);
                }
            }
#pragma unroll
            for (int u = 0; u < 7; ++u) {
                if (u < ns) {
                    const int s = sl[u];
#pragma unroll
                    for (int dd = 0; dd < 2; ++dd) {
                        const int j = dd * 64 + lane;       // qword index in slice
                        const int b = j >> 3;
                        const int colL = (j & 7) * 2;
                        const int col = s * 16 + colL;
                        const unsigned long long qv = v[u][dd];
                        const unsigned int d0 = (unsigned int)qv;
                        const unsigned int d1 = (unsigned int)(qv >> 32);
                        const unsigned int hpair = (d0 & 0xFFFFu) | (d1 << 16);
                        const unsigned int cpair = (d0 >> 16) | (d1 & 0xFFFF0000u);
                        const int fi = ((col >> 3) * 16 + b) * 8 + (col & 7);
                        *(unsigned int*)((f16*)A_sm + fi) = hpair;
                        *(unsigned int*)((f16*)C_sm + fi) = cpair;
                    }
                }
            }

            // stage x(t+1) into A_sm kb 64..95
            if (tid < 256) {
#pragma unroll
                for (int k2 = 0; k2 < 4; ++k2) {
                    const int idx = k2 * 256 + tid;
                    const int b = idx >> 6;
                    const int kx0 = (idx & 63) << 2;
                    union { f16 h[4]; uint2 u; } p;
                    p.h[0] = (f16)xv[k2].x; p.h[1] = (f16)xv[k2].y;
                    p.h[2] = (f16)xv[k2].z; p.h[3] = (f16)xv[k2].w;
                    const int kb = 64 + (kx0 >> 3), e = kx0 & 7;
                    *(uint2*)&A_sm[(kb * 16 + b) * 8 + e] = p.u;
                }
            }
            __syncthreads();
        }
    }
}

extern "C" void kernel_launch(void* const* d_in, const int* in_sizes, int n_in,
                              void* d_out, int out_size, void* d_ws, size_t ws_size,
                              hipStream_t stream) {
    const float* inputs  = (const float*)d_in[0];
    const float* tstamps = (const float*)d_in[1];
    const int*   lens    = (const int*)d_in[2];
    const float* W_all   = (const float*)d_in[3];
    const float* b_all   = (const float*)d_in[4];
    const float* U_all   = (const float*)d_in[5];
    const float* b_u     = (const float*)d_in[6];
    const float* W_d     = (const float*)d_in[7];
    const float* b_d     = (const float*)d_in[8];

    float* out0 = (float*)d_out;                    // [64,1024,512]
    float* out1 = out0 + (size_t)64 * 1024 * 512;   // last_h [64,512]
    float* out2 = out1 + (size_t)64 * 512;          // last_c [64,512]

    char* ws = (char*)d_ws;
    unsigned int* flags = (unsigned int*)ws;                       // 4 grp * 32 dwords
    unsigned long long* hcbuf = (unsigned long long*)(ws + 1024);  // 4 grp * 2 * 32KB = 256KB

    // flags must start at 0 every call (ws is poisoned 0xAA)
    hipMemsetAsync(ws, 0, 1024, stream);

    tlstm_scan<<<dim3(128), dim3(320), 0, stream>>>(
        inputs, tstamps, lens, W_all, b_all, U_all, b_u, W_d, b_d,
        out0, out1, out2, hcbuf, flags);
}